// Round 3
// baseline (1029.383 us; speedup 1.0000x reference)
//
#include <hip/hip_runtime.h>
#include <stdint.h>

// Fixed problem shape: outputs [8,16,384,384] fp32
#define B_ 8
#define D_ 16
#define H_ 384
#define W_ 384
constexpr int HW   = H_ * W_;     // 147456
constexpr int DHW  = D_ * HW;     // 2359296
constexpr int NTOT = B_ * DHW;    // 18874368
constexpr int NCOL = B_ * HW;     // 1179648

constexpr float T_LOW  = 0.8f;
constexpr float T_HIGH = 0.92f;
constexpr unsigned DUST_MIN = 20u;

// tile: full z, 8 x 32 in (h,w) -> 4096 voxels
constexpr int TZ = 16, TH = 8, TW = 32;
constexpr int TILE = 4096;
constexpr int THB = H_ / TH;              // 48
constexpr int TWB = W_ / TW;              // 12
constexpr int TILES_PER_B = THB * TWB;    // 576
constexpr int NTILES = B_ * TILES_PER_B;  // 4608

// boundary strips per tile: R[128] L[128] B[512] T[512] (u16 local-root slots)
constexpr int STRIP = 1280;
constexpr int WE_PER_B = THB * (TWB - 1) * 128;   // 67584
constexpr int HE_PER_B = (THB - 1) * TWB * 512;   // 288768
constexpr int E_PER_B  = WE_PER_B + HE_PER_B;     // 356352
constexpr int NEDGES   = B_ * E_PER_B;            // 2850816

// ---------- global union-find over ids = tile*4096 + slot ----------
// parent[] semantics: value < NTOT -> parent pointer; value >= NTOT -> root,
// with aggregated count = 0xFFFFFFFF - value (memset 0xFF => root, count 0).
__device__ __forceinline__ unsigned gfind(const unsigned* A, unsigned x) {
    unsigned p = A[x];
    while (p < (unsigned)NTOT) { x = p; p = A[x]; }
    return x;
}

__device__ __forceinline__ void gunite(unsigned* A, unsigned a, unsigned b) {
    for (;;) {
        a = gfind(A, a);
        b = gfind(A, b);
        if (a == b) return;
        unsigned lo = a < b ? a : b;
        unsigned hi = a < b ? b : a;
        unsigned old = atomicMin(&A[hi], lo);
        if (old >= (unsigned)NTOT) return;   // hi was a root, now linked
        a = lo; b = old;
    }
}

// walk to root, return its aggregated count
__device__ __forceinline__ unsigned query_count(const unsigned* A, unsigned gid) {
    unsigned p = A[gid];
    while (p < (unsigned)NTOT) { gid = p; p = A[gid]; }
    return 0xFFFFFFFFu - p;
}

// ---------- LDS union-find ----------
__device__ __forceinline__ unsigned luf_find(volatile unsigned* sl, unsigned x) {
    unsigned p = sl[x];
    while (p != x) { x = p; p = sl[x]; }
    return x;
}

__device__ __forceinline__ void luf_union(unsigned* sl, unsigned a, unsigned b) {
    for (;;) {
        a = luf_find(sl, a);
        b = luf_find(sl, b);
        if (a == b) return;
        unsigned lo = a < b ? a : b;
        unsigned hi = a < b ? b : a;
        unsigned old = atomicMin(&sl[hi], lo);
        if (old == hi) return;
        a = lo; b = old;
    }
}

// local CCL on fgbits (bit z = voxel (z, t) fg). Leaves sl converged.
// Includes barriers; every thread must call.
__device__ __forceinline__ void local_ccl(unsigned* sl, unsigned fgbits,
                                          int t, int lh, int lw) {
    #pragma unroll
    for (int z = 0; z < TZ; ++z)
        sl[z * 256 + t] = ((fgbits >> z) & 1) ? (unsigned)(z * 256 + t) : 0xFFFFFFFFu;
    __syncthreads();
    #pragma unroll
    for (int z = 0; z < TZ; ++z) {
        if (!((fgbits >> z) & 1)) continue;
        int lv = z * 256 + t;
        if (lw < TW - 1 && sl[lv + 1]   != 0xFFFFFFFFu) luf_union(sl, lv, lv + 1);
        if (lh < TH - 1 && sl[lv + 32]  != 0xFFFFFFFFu) luf_union(sl, lv, lv + 32);
        if (z  < TZ - 1 && sl[lv + 256] != 0xFFFFFFFFu) luf_union(sl, lv, lv + 256);
    }
    __syncthreads();
}

__device__ __forceinline__ void export_strips(unsigned* sl, unsigned fg,
                                              unsigned short* sb, int t, int lh, int lw) {
    if (lw == TW - 1) {
        #pragma unroll
        for (int z = 0; z < TZ; ++z)
            sb[z * 8 + lh] = ((fg >> z) & 1) ? (unsigned short)luf_find(sl, z * 256 + t) : 0xFFFFu;
    }
    if (lw == 0) {
        #pragma unroll
        for (int z = 0; z < TZ; ++z)
            sb[128 + z * 8 + lh] = ((fg >> z) & 1) ? (unsigned short)luf_find(sl, z * 256 + t) : 0xFFFFu;
    }
    if (lh == TH - 1) {
        #pragma unroll
        for (int z = 0; z < TZ; ++z)
            sb[256 + z * 32 + lw] = ((fg >> z) & 1) ? (unsigned short)luf_find(sl, z * 256 + t) : 0xFFFFu;
    }
    if (lh == 0) {
        #pragma unroll
        for (int z = 0; z < TZ; ++z)
            sb[768 + z * 32 + lw] = ((fg >> z) & 1) ? (unsigned short)luf_find(sl, z * 256 + t) : 0xFFFFu;
    }
}

// ---------------- kernels ----------------

// read x -> packed weak/strong cols; local CCL on weak; export strips
__global__ __launch_bounds__(256) void k_phase1(const float* __restrict__ x,
                                                unsigned* __restrict__ cols,
                                                unsigned short* __restrict__ strips) {
    __shared__ unsigned sl[TILE];
    int tile = blockIdx.x;
    int b = tile / TILES_PER_B, tr = tile % TILES_PER_B;
    int h0 = (tr / TWB) * TH, w0 = (tr % TWB) * TW;
    int t = threadIdx.x, lh = t >> 5, lw = t & 31;
    int colg = b * HW + (h0 + lh) * W_ + (w0 + lw);
    int base = b * DHW + (h0 + lh) * W_ + (w0 + lw);

    unsigned wk = 0, st = 0;
    #pragma unroll
    for (int z = 0; z < TZ; ++z) {
        float v = x[base + z * HW];
        wk |= (v >= T_LOW  ? 1u : 0u) << z;
        st |= (v >= T_HIGH ? 1u : 0u) << z;
    }
    cols[colg] = wk | (st << 16);
    local_ccl(sl, wk, t, lh, lw);
    export_strips(sl, wk, strips + (size_t)tile * STRIP, t, lh, lw);
}

// cross-tile unions from boundary strips
__global__ void k_edges(const unsigned short* __restrict__ strips, unsigned* parent) {
    int e = blockIdx.x * blockDim.x + threadIdx.x;
    if (e >= NEDGES) return;
    int b = e / E_PER_B, r = e % E_PER_B;
    int tileA, tileB, offA, offB;
    if (r < WE_PER_B) {
        int th = r / ((TWB - 1) * 128), r2 = r % ((TWB - 1) * 128);
        int wp = r2 / 128, k = r2 % 128;
        tileA = b * TILES_PER_B + th * TWB + wp; tileB = tileA + 1;
        offA = k; offB = 128 + k;
    } else {
        r -= WE_PER_B;
        int hp = r / (TWB * 512), r2 = r % (TWB * 512);
        int tw = r2 / 512, k = r2 % 512;
        tileA = b * TILES_PER_B + hp * TWB + tw; tileB = tileA + TWB;
        offA = 256 + k; offB = 768 + k;
    }
    unsigned sA = strips[(size_t)tileA * STRIP + offA];
    unsigned sB = strips[(size_t)tileB * STRIP + offB];
    if (sA == 0xFFFFu || sB == 0xFFFFu) return;
    gunite(parent, (unsigned)tileA * TILE + sA, (unsigned)tileB * TILE + sB);
}

// re-run weak CCL; aggregate per-local-root strong counts into global roots
__global__ __launch_bounds__(256) void k_agg1(const unsigned* __restrict__ cols,
                                              unsigned* parent) {
    __shared__ unsigned sl[TILE];
    __shared__ unsigned cnt[TILE];
    int tile = blockIdx.x;
    int b = tile / TILES_PER_B, tr = tile % TILES_PER_B;
    int h0 = (tr / TWB) * TH, w0 = (tr % TWB) * TW;
    int t = threadIdx.x, lh = t >> 5, lw = t & 31;
    unsigned cc = cols[b * HW + (h0 + lh) * W_ + (w0 + lw)];
    unsigned wk = cc & 0xFFFFu, st = cc >> 16;
    #pragma unroll
    for (int z = 0; z < TZ; ++z) cnt[z * 256 + t] = 0;   // before local_ccl's barrier
    local_ccl(sl, wk, t, lh, lw);
    #pragma unroll
    for (int z = 0; z < TZ; ++z)
        if ((st >> z) & 1) atomicAdd(&cnt[luf_find(sl, z * 256 + t)], 1u);
    __syncthreads();
    #pragma unroll
    for (int z = 0; z < TZ; ++z) {
        int lv = z * 256 + t;
        if (((wk >> z) & 1) && sl[lv] == (unsigned)lv && cnt[lv] > 0) {
            unsigned gid = (unsigned)tile * TILE + lv;
            unsigned rt = gfind(parent, gid);
            atomicSub(&parent[rt], cnt[lv]);
        }
    }
}

// hysteresis (comp strong-count > 0) + z-closing -> closedcols;
// then local CCL on closed mask + export strips
__global__ __launch_bounds__(256) void k_close(const unsigned* __restrict__ cols,
                                               const unsigned* __restrict__ parent,
                                               unsigned short* __restrict__ closedcols,
                                               unsigned short* __restrict__ strips) {
    __shared__ unsigned sl[TILE];
    __shared__ unsigned flag[TILE];
    int tile = blockIdx.x;
    int b = tile / TILES_PER_B, tr = tile % TILES_PER_B;
    int h0 = (tr / TWB) * TH, w0 = (tr % TWB) * TW;
    int t = threadIdx.x, lh = t >> 5, lw = t & 31;
    int colg = b * HW + (h0 + lh) * W_ + (w0 + lw);
    unsigned wk = cols[colg] & 0xFFFFu;

    local_ccl(sl, wk, t, lh, lw);
    #pragma unroll
    for (int z = 0; z < TZ; ++z) {
        int lv = z * 256 + t;
        if (((wk >> z) & 1) && sl[lv] == (unsigned)lv)
            flag[lv] = (query_count(parent, (unsigned)tile * TILE + lv) > 0) ? 1u : 0u;
    }
    __syncthreads();
    unsigned m = 0;
    #pragma unroll
    for (int z = 0; z < TZ; ++z)
        if ((wk >> z) & 1)
            if (flag[luf_find(sl, z * 256 + t)]) m |= 1u << z;
    // closing along z: dilate (OOB=bg), erode (OOB=fg)
    unsigned dil = (m | (m << 1) | (m >> 1)) & 0xFFFFu;
    unsigned ero = dil & ((dil << 1) | 1u) & ((dil >> 1) | 0x8000u);
    closedcols[colg] = (unsigned short)ero;
    __syncthreads();                       // all reads of old sl done
    local_ccl(sl, ero, t, lh, lw);
    export_strips(sl, ero, strips + (size_t)tile * STRIP, t, lh, lw);
}

// re-run closed CCL; aggregate per-local-root sizes into global roots
__global__ __launch_bounds__(256) void k_agg2(const unsigned short* __restrict__ closedcols,
                                              unsigned* parent) {
    __shared__ unsigned sl[TILE];
    __shared__ unsigned cnt[TILE];
    int tile = blockIdx.x;
    int b = tile / TILES_PER_B, tr = tile % TILES_PER_B;
    int h0 = (tr / TWB) * TH, w0 = (tr % TWB) * TW;
    int t = threadIdx.x, lh = t >> 5, lw = t & 31;
    unsigned fg = closedcols[b * HW + (h0 + lh) * W_ + (w0 + lw)];
    #pragma unroll
    for (int z = 0; z < TZ; ++z) cnt[z * 256 + t] = 0;
    local_ccl(sl, fg, t, lh, lw);
    #pragma unroll
    for (int z = 0; z < TZ; ++z)
        if ((fg >> z) & 1) atomicAdd(&cnt[luf_find(sl, z * 256 + t)], 1u);
    __syncthreads();
    #pragma unroll
    for (int z = 0; z < TZ; ++z) {
        int lv = z * 256 + t;
        if (((fg >> z) & 1) && sl[lv] == (unsigned)lv) {
            unsigned gid = (unsigned)tile * TILE + lv;
            unsigned rt = gfind(parent, gid);
            atomicSub(&parent[rt], cnt[lv]);
        }
    }
}

// re-run closed CCL; keep components with global size >= DUST_MIN; write output
__global__ __launch_bounds__(256) void k_out(const unsigned short* __restrict__ closedcols,
                                             const unsigned* __restrict__ parent,
                                             float* __restrict__ out) {
    __shared__ unsigned sl[TILE];
    __shared__ unsigned keep[TILE];
    int tile = blockIdx.x;
    int b = tile / TILES_PER_B, tr = tile % TILES_PER_B;
    int h0 = (tr / TWB) * TH, w0 = (tr % TWB) * TW;
    int t = threadIdx.x, lh = t >> 5, lw = t & 31;
    int base = b * DHW + (h0 + lh) * W_ + (w0 + lw);
    unsigned fg = closedcols[b * HW + (h0 + lh) * W_ + (w0 + lw)];

    local_ccl(sl, fg, t, lh, lw);
    #pragma unroll
    for (int z = 0; z < TZ; ++z) {
        int lv = z * 256 + t;
        if (((fg >> z) & 1) && sl[lv] == (unsigned)lv)
            keep[lv] = (query_count(parent, (unsigned)tile * TILE + lv) >= DUST_MIN) ? 1u : 0u;
    }
    __syncthreads();
    #pragma unroll
    for (int z = 0; z < TZ; ++z) {
        float o = 0.0f;
        if ((fg >> z) & 1)
            if (keep[luf_find(sl, z * 256 + t)]) o = 1.0f;
        out[base + z * HW] = o;
    }
}

extern "C" void kernel_launch(void* const* d_in, const int* in_sizes, int n_in,
                              void* d_out, int out_size, void* d_ws, size_t ws_size,
                              hipStream_t stream) {
    const float* x = (const float*)d_in[0];
    float* out = (float*)d_out;

    // ws: parent [NTOT u32] | cols [NCOL u32] | closedcols [NCOL u16] | strips [NTILES*1280 u16]
    const size_t sz_parent = (size_t)NTOT * 4;
    const size_t sz_cols   = (size_t)NCOL * 4;
    const size_t sz_closed = (size_t)NCOL * 2;
    const size_t sz_strips = (size_t)NTILES * STRIP * 2;
    if (ws_size < sz_parent + sz_cols + sz_closed + sz_strips) return;
    char* ws = (char*)d_ws;
    unsigned*       parent = (unsigned*)ws;
    unsigned*       cols   = (unsigned*)(ws + sz_parent);
    unsigned short* closed = (unsigned short*)(ws + sz_parent + sz_cols);
    unsigned short* strips = (unsigned short*)(ws + sz_parent + sz_cols + sz_closed);

    dim3 blk(256);
    dim3 grdT(NTILES);
    dim3 grdE((NEDGES + 255) / 256);

    // ---- phase 1: weak CCL + hysteresis flags ----
    hipMemsetAsync(parent, 0xFF, sz_parent, stream);
    k_phase1<<<grdT, blk, 0, stream>>>(x, cols, strips);
    k_edges<<<grdE, blk, 0, stream>>>(strips, parent);
    k_agg1<<<grdT, blk, 0, stream>>>(cols, parent);
    k_close<<<grdT, blk, 0, stream>>>(cols, parent, closed, strips);

    // ---- phase 2: closed CCL + dust removal ----
    hipMemsetAsync(parent, 0xFF, sz_parent, stream);
    k_edges<<<grdE, blk, 0, stream>>>(strips, parent);
    k_agg2<<<grdT, blk, 0, stream>>>(closed, parent);
    k_out<<<grdT, blk, 0, stream>>>(closed, parent, out);
}

// Round 4
// 559.460 us; speedup vs baseline: 1.8400x; 1.8400x over previous
//
#include <hip/hip_runtime.h>
#include <stdint.h>

// Fixed problem shape: outputs [8,16,384,384] fp32
#define B_ 8
#define D_ 16
#define H_ 384
#define W_ 384
constexpr int HW   = H_ * W_;     // 147456
constexpr int DHW  = D_ * HW;     // 2359296
constexpr int NTOT = B_ * DHW;    // 18874368
constexpr int NCOL = B_ * HW;     // 1179648 (one per (b,h,w) column)
constexpr unsigned NRUN = (unsigned)NCOL * 8u;  // run-id space: column*8 + run_idx

constexpr float T_LOW  = 0.8f;
constexpr float T_HIGH = 0.92f;
constexpr unsigned DUST_MIN = 20u;

constexpr int NBLK = NCOL / 256;  // 4608, exact

// ---------- global union-find over z-run ids ----------
// parent[] semantics: value < NRUN -> parent pointer; value >= NRUN -> root,
// aggregated count = 0xFFFFFFFF - value (memset 0xFF => root, count 0).
__device__ __forceinline__ unsigned gfind(const unsigned* A, unsigned x) {
    unsigned p = A[x];
    while (p < NRUN) { x = p; p = A[x]; }
    return x;
}

// walk to root, return the root's VALUE (>= NRUN); count = 0xFFFFFFFF - value
__device__ __forceinline__ unsigned groot_val(const unsigned* A, unsigned x) {
    unsigned p = A[x];
    while (p < NRUN) { x = p; p = A[x]; }
    return p;
}

__device__ __forceinline__ void gunite(unsigned* A, unsigned a, unsigned b) {
    for (;;) {
        a = gfind(A, a);
        b = gfind(A, b);
        if (a == b) return;
        unsigned lo = a < b ? a : b;
        unsigned hi = a < b ? b : a;
        unsigned old = atomicMin(&A[hi], lo);
        if (old >= NRUN) return;   // hi was a root, now linked to lo
        a = lo; b = old;
    }
}

// run index containing bit p of mask m (p must be a set bit)
__device__ __forceinline__ int runidx(unsigned m, int p) {
    unsigned starts = m & ~(m << 1);
    return __popc(starts & ((2u << p) - 1u)) - 1;
}

// union runs of columns cA/cB wherever their masks overlap in z
__device__ __forceinline__ void unite_overlaps(unsigned* parent, int cA, unsigned mA,
                                               int cB, unsigned mB) {
    unsigned ov = mA & mB;
    while (ov) {
        int p = __ffs(ov) - 1;
        gunite(parent, (unsigned)cA * 8u + runidx(mA, p),
                       (unsigned)cB * 8u + runidx(mB, p));
        ov &= ov + (1u << p);   // clear the contiguous overlap segment at p
    }
}

// ---------------- kernels (all: 1 thread = 1 column, fully coalesced) ----------------

// read x -> packed weak|strong column masks
__global__ __launch_bounds__(256) void k_cols(const float* __restrict__ x,
                                              unsigned* __restrict__ cols) {
    int c = blockIdx.x * 256 + threadIdx.x;
    int b = c / HW, p = c - b * HW;
    const float* xp = x + (size_t)b * DHW + p;
    unsigned wk = 0, st = 0;
    #pragma unroll
    for (int z = 0; z < D_; ++z) {
        float v = xp[(size_t)z * HW];
        wk |= (v >= T_LOW  ? 1u : 0u) << z;
        st |= (v >= T_HIGH ? 1u : 0u) << z;
    }
    cols[c] = wk | (st << 16);
}

// unions between overlapping weak runs of (c, c+1) and (c, c+W) columns
__global__ __launch_bounds__(256) void k_union1(const unsigned* __restrict__ cols,
                                                unsigned* parent) {
    int c = blockIdx.x * 256 + threadIdx.x;
    unsigned mA = cols[c] & 0xFFFFu;
    if (!mA) return;
    int w = c % W_;
    int h = (c / W_) % H_;
    if (w < W_ - 1) {
        unsigned mB = cols[c + 1] & 0xFFFFu;
        if (mA & mB) unite_overlaps(parent, c, mA, c + 1, mB);
    }
    if (h < H_ - 1) {
        unsigned mB = cols[c + W_] & 0xFFFFu;
        if (mA & mB) unite_overlaps(parent, c, mA, c + W_, mB);
    }
}

// aggregate per-run strong counts into component roots
__global__ __launch_bounds__(256) void k_agg1(const unsigned* __restrict__ cols,
                                              unsigned* parent) {
    int c = blockIdx.x * 256 + threadIdx.x;
    unsigned cc = cols[c];
    unsigned wk = cc & 0xFFFFu, st = cc >> 16;
    if (!st) return;
    unsigned rem = wk; int idx = 0;
    while (rem) {
        int p = __ffs(rem) - 1;
        unsigned t = rem >> p;
        int len = __ffs(~t) - 1;
        unsigned runmask = ((1u << len) - 1u) << p;
        unsigned sc = (unsigned)__popc(runmask & st);
        if (sc) {
            unsigned r = gfind(parent, (unsigned)c * 8u + idx);
            atomicSub(&parent[r], sc);
        }
        rem &= ~runmask; ++idx;
    }
}

// hysteresis (component strong-count > 0) + z-closing -> closed column masks
__global__ __launch_bounds__(256) void k_close(const unsigned* __restrict__ cols,
                                               const unsigned* __restrict__ parent,
                                               unsigned short* __restrict__ closed) {
    int c = blockIdx.x * 256 + threadIdx.x;
    unsigned wk = cols[c] & 0xFFFFu;
    unsigned m = 0;
    unsigned rem = wk; int idx = 0;
    while (rem) {
        int p = __ffs(rem) - 1;
        unsigned t = rem >> p;
        int len = __ffs(~t) - 1;
        unsigned runmask = ((1u << len) - 1u) << p;
        if (groot_val(parent, (unsigned)c * 8u + idx) != 0xFFFFFFFFu)  // count > 0
            m |= runmask;
        rem &= ~runmask; ++idx;
    }
    // closing along z: dilate (OOB = background), erode (OOB = foreground)
    unsigned dil = (m | (m << 1) | (m >> 1)) & 0xFFFFu;
    unsigned ero = dil & ((dil << 1) | 1u) & ((dil >> 1) | 0x8000u);
    closed[c] = (unsigned short)ero;
}

// unions between overlapping closed runs
__global__ __launch_bounds__(256) void k_union2(const unsigned short* __restrict__ closed,
                                                unsigned* parent) {
    int c = blockIdx.x * 256 + threadIdx.x;
    unsigned mA = closed[c];
    if (!mA) return;
    int w = c % W_;
    int h = (c / W_) % H_;
    if (w < W_ - 1) {
        unsigned mB = closed[c + 1];
        if (mA & mB) unite_overlaps(parent, c, mA, c + 1, mB);
    }
    if (h < H_ - 1) {
        unsigned mB = closed[c + W_];
        if (mA & mB) unite_overlaps(parent, c, mA, c + W_, mB);
    }
}

// aggregate per-run voxel counts into component roots
__global__ __launch_bounds__(256) void k_agg2(const unsigned short* __restrict__ closed,
                                              unsigned* parent) {
    int c = blockIdx.x * 256 + threadIdx.x;
    unsigned fg = closed[c];
    if (!fg) return;
    unsigned rem = fg; int idx = 0;
    while (rem) {
        int p = __ffs(rem) - 1;
        unsigned t = rem >> p;
        int len = __ffs(~t) - 1;
        unsigned runmask = ((1u << len) - 1u) << p;
        unsigned r = gfind(parent, (unsigned)c * 8u + idx);
        atomicSub(&parent[r], (unsigned)__popc(runmask));
        rem &= ~runmask; ++idx;
    }
}

// keep components with size >= DUST_MIN; write 0/1 float output
__global__ __launch_bounds__(256) void k_out(const unsigned short* __restrict__ closed,
                                             const unsigned* __restrict__ parent,
                                             float* __restrict__ out) {
    int c = blockIdx.x * 256 + threadIdx.x;
    unsigned fg = closed[c];
    unsigned keep = 0;
    unsigned rem = fg; int idx = 0;
    while (rem) {
        int p = __ffs(rem) - 1;
        unsigned t = rem >> p;
        int len = __ffs(~t) - 1;
        unsigned runmask = ((1u << len) - 1u) << p;
        if (0xFFFFFFFFu - groot_val(parent, (unsigned)c * 8u + idx) >= DUST_MIN)
            keep |= runmask;
        rem &= ~runmask; ++idx;
    }
    int b = c / HW, p2 = c - b * HW;
    float* op = out + (size_t)b * DHW + p2;
    #pragma unroll
    for (int z = 0; z < D_; ++z)
        op[(size_t)z * HW] = ((keep >> z) & 1u) ? 1.0f : 0.0f;
}

extern "C" void kernel_launch(void* const* d_in, const int* in_sizes, int n_in,
                              void* d_out, int out_size, void* d_ws, size_t ws_size,
                              hipStream_t stream) {
    const float* x = (const float*)d_in[0];
    float* out = (float*)d_out;

    // ws: parent [NRUN u32] | cols [NCOL u32] | closed [NCOL u16]
    const size_t sz_parent = (size_t)NRUN * 4;
    const size_t sz_cols   = (size_t)NCOL * 4;
    const size_t sz_closed = (size_t)NCOL * 2;
    if (ws_size < sz_parent + sz_cols + sz_closed) return;
    char* ws = (char*)d_ws;
    unsigned*       parent = (unsigned*)ws;
    unsigned*       cols   = (unsigned*)(ws + sz_parent);
    unsigned short* closed = (unsigned short*)(ws + sz_parent + sz_cols);

    dim3 blk(256), grd(NBLK);

    // ---- phase 1: weak-run CCL + hysteresis ----
    hipMemsetAsync(parent, 0xFF, sz_parent, stream);
    k_cols<<<grd, blk, 0, stream>>>(x, cols);
    k_union1<<<grd, blk, 0, stream>>>(cols, parent);
    k_agg1<<<grd, blk, 0, stream>>>(cols, parent);
    k_close<<<grd, blk, 0, stream>>>(cols, parent, closed);

    // ---- phase 2: closed-run CCL + dust removal ----
    hipMemsetAsync(parent, 0xFF, sz_parent, stream);
    k_union2<<<grd, blk, 0, stream>>>(closed, parent);
    k_agg2<<<grd, blk, 0, stream>>>(closed, parent);
    k_out<<<grd, blk, 0, stream>>>(closed, parent, out);
}